// Round 2
// 679.387 us; speedup vs baseline: 1.0553x; 1.0553x over previous
//
#include <hip/hip_runtime.h>

#define B_ 4
#define S_ 4096
#define D_ 2048
#define H_ 8192
#define KCAP 491
#define SLOTP 512
#define MPAD 2048  // B_ * SLOTP

typedef __attribute__((ext_vector_type(8))) short short8;
typedef __attribute__((ext_vector_type(4))) float float4_t;

__device__ __forceinline__ unsigned short f2bf(float f) {
    unsigned int u = __float_as_uint(f);
    unsigned int r = u + 0x7fffu + ((u >> 16) & 1u);
    return (unsigned short)(r >> 16);
}

__device__ __forceinline__ void gload_lds16(const void* g, void* l) {
    __builtin_amdgcn_global_load_lds((const __attribute__((address_space(1))) void*)g,
                                     (__attribute__((address_space(3))) void*)l, 16, 0, 0);
}

// ---------------- transpose + f32->bf16 cast ----------------
// mode < 0 : out[c][r] = cast(in[r][c])                      (plain, for W2)
// mode >= 0: out row = ((c>>4)<<5) | (c&15) | mode           (16-col interleave of W1/W3
//            into a combined [16384][2048] B^T buffer; mode=0 -> W1, mode=16 -> W3)
__global__ __launch_bounds__(256) void k_transpose_bf16(const float* __restrict__ in,
                                                        unsigned short* __restrict__ out,
                                                        int R, int C, int mode) {
    __shared__ float s[64][65];
    int t = threadIdx.x;
    int tx = t & 15, ty = t >> 4;
    int r0 = blockIdx.x * 64, c0 = blockIdx.y * 64;
#pragma unroll
    for (int q = 0; q < 4; q++) {
        int r = ty + q * 16;
        float4 v = *(const float4*)(in + (size_t)(r0 + r) * C + c0 + tx * 4);
        s[r][tx * 4 + 0] = v.x;
        s[r][tx * 4 + 1] = v.y;
        s[r][tx * 4 + 2] = v.z;
        s[r][tx * 4 + 3] = v.w;
    }
    __syncthreads();
#pragma unroll
    for (int q = 0; q < 4; q++) {
        int c = ty + q * 16;
        int cg = c0 + c;
        int orow = (mode < 0) ? cg : ((((cg >> 4) << 5) | (cg & 15)) | mode);
        ushort4 o;
        o.x = f2bf(s[tx * 4 + 0][c]);
        o.y = f2bf(s[tx * 4 + 1][c]);
        o.z = f2bf(s[tx * 4 + 2][c]);
        o.w = f2bf(s[tx * 4 + 3][c]);
        *(ushort4*)(out + (size_t)orow * R + r0 + tx * 4) = o;
    }
}

// ---------------- fused: out = x copy + router logits (f64 accum) ----------------
__global__ __launch_bounds__(256) void k_router_copy(const float* __restrict__ x,
                                                     const float* __restrict__ Wr,
                                                     const float* __restrict__ Wa,
                                                     float* __restrict__ out,
                                                     float* __restrict__ logits,
                                                     float* __restrict__ auxlog) {
    int w = threadIdx.x >> 6, lane = threadIdx.x & 63;
    int row = blockIdx.x * 4 + w;
    const float* xr = x + (size_t)row * D_;
    float* orow = out + (size_t)row * D_;
    double sr = 0.0, sa = 0.0;
#pragma unroll
    for (int it = 0; it < 8; it++) {
        int off = it * 256 + lane * 4;
        float4 xv = *(const float4*)(xr + off);
        float4 rv = *(const float4*)(Wr + off);
        float4 av = *(const float4*)(Wa + off);
        *(float4*)(orow + off) = xv;
        sr += (double)xv.x * rv.x + (double)xv.y * rv.y + (double)xv.z * rv.z + (double)xv.w * rv.w;
        sa += (double)xv.x * av.x + (double)xv.y * av.y + (double)xv.z * av.z + (double)xv.w * av.w;
    }
#pragma unroll
    for (int off = 32; off > 0; off >>= 1) {
        sr += __shfl_down(sr, off);
        sa += __shfl_down(sa, off);
    }
    if (lane == 0) {
        logits[row] = (float)sr;
        auxlog[row] = (float)sa;
    }
}

// ---------------- per-batch top-k via bitonic sort ----------------
__global__ __launch_bounds__(1024) void k_topk(const float* __restrict__ logits,
                                               int* __restrict__ sel, float* __restrict__ rw,
                                               int* __restrict__ flags) {
    __shared__ unsigned long long keys[S_];
    __shared__ int sarr[SLOTP];
    int b = blockIdx.x, tid = threadIdx.x;
    const float* lg = logits + (size_t)b * S_;
    for (int i = tid; i < S_; i += 1024) {
        unsigned u = __float_as_uint(lg[i]);
        u = (u & 0x80000000u) ? ~u : (u | 0x80000000u);
        keys[i] = ((unsigned long long)u << 32) | (unsigned)(S_ - 1 - i);
    }
    __syncthreads();
    for (int k = 2; k <= S_; k <<= 1) {
        for (int j = k >> 1; j > 0; j >>= 1) {
            for (int s = tid; s < S_ / 2; s += 1024) {
                int i = 2 * s - (s & (j - 1));
                int ixj = i | j;
                bool up = ((i & k) == 0);
                unsigned long long a = keys[i], c = keys[ixj];
                if ((a < c) == up) { keys[i] = c; keys[ixj] = a; }
            }
            __syncthreads();
        }
    }
    if (tid < KCAP) sarr[tid] = (int)(S_ - 1 - (unsigned)(keys[tid] & 0xFFFFFFFFull));
    __syncthreads();
    if (tid < KCAP) {
        int s = sarr[tid];
        int rank = 0;
        for (int j = 0; j < KCAP; j++) rank += (sarr[j] < s) ? 1 : 0;
        sel[b * SLOTP + rank] = s;
        rw[b * SLOTP + rank] = lg[s];
        flags[s] = 1;
    } else if (tid < SLOTP) {
        sel[b * SLOTP + tid] = 0;
        rw[b * SLOTP + tid] = 0.f;
    }
}

// ---------------- gather selected tokens -> bf16 A [MPAD][D_] ----------------
__global__ __launch_bounds__(256) void k_gather(const float* __restrict__ x,
                                                const int* __restrict__ sel,
                                                unsigned short* __restrict__ Abuf) {
    int row = blockIdx.x;
    int b = row >> 9, slot = row & 511;
    int tid = threadIdx.x;
    unsigned short* dst = Abuf + (size_t)row * D_ + tid * 8;
    if (slot < KCAP) {
        int tok = sel[b * SLOTP + slot];
        const float* src = x + ((size_t)(b * S_ + tok)) * D_ + tid * 8;
        float4 v0 = *(const float4*)(src);
        float4 v1 = *(const float4*)(src + 4);
        union { unsigned short us[8]; uint4 v; } pk;
        pk.us[0] = f2bf(v0.x); pk.us[1] = f2bf(v0.y); pk.us[2] = f2bf(v0.z); pk.us[3] = f2bf(v0.w);
        pk.us[4] = f2bf(v1.x); pk.us[5] = f2bf(v1.y); pk.us[6] = f2bf(v1.z); pk.us[7] = f2bf(v1.w);
        *(uint4*)dst = pk.v;
    } else {
        *(uint4*)dst = make_uint4(0u, 0u, 0u, 0u);
    }
}

// ============================================================================
// GEMM structure (both kernels): 256x256 tile, BK=32, 8 waves (2M x 4N),
// per-wave 128x64 output (8x4 fragments), triple-buffered LDS (3 x 32KB),
// counted vmcnt (never drained in main loop), raw s_barrier, T2 XOR swizzle
// slot ^= (row>>1)&3 via pre-swizzled global source + swizzled ds_read,
// T5 setprio around the MFMA cluster.
// Race-freedom: tile t+2 writes the buffer tile t-1 used; all ds_reads of that
// buffer completed (lgkm-waited before MFMA) before the previous s_barrier
// (pinned by sched_barrier(0)), and the gload issue happens after it. The
// "memory" clobber on the vmcnt asm stops the compiler hoisting next-buffer
// ds_reads above the wait; FIFO vmcnt semantics guarantee tile t+1 landed.
// ============================================================================

// ---------------- GEMM1: H = swiglu(A @ Wc^T), Wc = 16-col-interleaved [W1|W3] ----------------
__global__ __launch_bounds__(512, 2) void k_gemm1(const unsigned short* __restrict__ A,
                                                  const unsigned short* __restrict__ Bc,
                                                  unsigned short* __restrict__ Hbuf) {
    __shared__ unsigned short lds[3 * 16384];  // 96KB: per buf [A 256x32 | B 256x32]
    const int tid = threadIdx.x;
    const int w = tid >> 6, lane = tid & 63;
    const int wr = w >> 2, wc = w & 3;
    const int lrow = lane & 15, l16 = lane >> 4;
    const int w64 = tid & ~63;

    // XCD-aware swizzle: 512 wgs, 64 per XCD -> each XCD owns one full A-panel (mblk)
    int bid = blockIdx.x;
    int m0 = (bid & 7) * 256;   // 8 m-blocks
    int n0 = (bid >> 3) * 256;  // 64 n-blocks over N'=16384

    const unsigned short* gA = A + (size_t)m0 * D_;
    const unsigned short* gB = Bc + (size_t)n0 * D_;

    // staging: 1024 16B-chunks per matrix, 2 issues each; source pre-swizzled
    int goff[2], dstA[2], dstB[2];
#pragma unroll
    for (int q = 0; q < 2; q++) {
        int i = q * 512 + tid;
        int row = i >> 2;
        int slot = (i & 3) ^ ((row >> 1) & 3);
        goff[q] = row * D_ + slot * 8;
        dstA[q] = (q * 512 + w64) * 8;
        dstB[q] = 8192 + (q * 512 + w64) * 8;
    }

    // fragment LDS offsets (swizzled read side)
    int offA[8], offB[4];
#pragma unroll
    for (int i = 0; i < 8; i++) {
        int r = wr * 128 + i * 16 + lrow;
        offA[i] = r * 32 + (l16 ^ ((r >> 1) & 3)) * 8;
    }
#pragma unroll
    for (int j = 0; j < 4; j++) {
        int r = wc * 64 + j * 16 + lrow;
        offB[j] = 8192 + r * 32 + (l16 ^ ((r >> 1) & 3)) * 8;
    }

    float4_t acc[8][4] = {};

#define STAGE1(buf, kt)                                       \
    {                                                         \
        unsigned short* sb_ = lds + (buf) * 16384;            \
        gload_lds16(gA + goff[0] + (kt), sb_ + dstA[0]);      \
        gload_lds16(gA + goff[1] + (kt), sb_ + dstA[1]);      \
        gload_lds16(gB + goff[0] + (kt), sb_ + dstB[0]);      \
        gload_lds16(gB + goff[1] + (kt), sb_ + dstB[1]);      \
    }

    STAGE1(0, 0);
    STAGE1(1, 32);
    asm volatile("s_waitcnt vmcnt(4)" ::: "memory");  // tile 0 landed, tile 1 in flight
    __builtin_amdgcn_s_barrier();

    const int NT = D_ / 32;  // 64
    int cur = 0, nx = 2;
    for (int t = 0; t < NT; t++) {
        if (t + 2 < NT) STAGE1(nx, (t + 2) * 32);
        const unsigned short* sb = lds + cur * 16384;
        short8 af[8], bf[4];
#pragma unroll
        for (int i = 0; i < 8; i++) af[i] = *(const short8*)(sb + offA[i]);
#pragma unroll
        for (int j = 0; j < 4; j++) bf[j] = *(const short8*)(sb + offB[j]);
        __builtin_amdgcn_s_setprio(1);
#pragma unroll
        for (int j = 0; j < 4; j++)
#pragma unroll
            for (int i = 0; i < 8; i++)
                acc[i][j] = __builtin_amdgcn_mfma_f32_16x16x32_bf16(af[i], bf[j], acc[i][j], 0, 0, 0);
        __builtin_amdgcn_s_setprio(0);
        if (t + 1 < NT) {
            __builtin_amdgcn_sched_barrier(0);  // pin reads+MFMA (and their lgkm waits) above barrier
            if (t + 2 < NT) asm volatile("s_waitcnt vmcnt(4)" ::: "memory");  // next tile landed
            else            asm volatile("s_waitcnt vmcnt(0)" ::: "memory");  // drain last tile
            __builtin_amdgcn_s_barrier();
        }
        cur = (cur == 2) ? 0 : cur + 1;
        nx  = (nx == 2) ? 0 : nx + 1;
    }
#undef STAGE1

    // SwiGLU epilogue: j even = g1 (W1), j odd = g2 (W3), same hidden col
#pragma unroll
    for (int i = 0; i < 8; i++) {
        int mbase = m0 + wr * 128 + i * 16 + l16 * 4;
#pragma unroll
        for (int jp = 0; jp < 2; jp++) {
            int np = n0 + wc * 64 + jp * 32 + lrow;       // n' of the g1 fragment
            int col = ((np >> 5) << 4) | (np & 15);       // drop interleave bit 4
#pragma unroll
            for (int r = 0; r < 4; r++) {
                float g1 = acc[i][2 * jp][r];
                float g2 = acc[i][2 * jp + 1][r];
                float hv = (g1 / (1.f + expf(-g1))) * g2;
                Hbuf[(size_t)(mbase + r) * H_ + col] = f2bf(hv);
            }
        }
    }
}

// ---------------- GEMM2 split-K=4: y = h @ W2, atomic scatter out += rw*y ----------------
__global__ __launch_bounds__(512, 2) void k_gemm2(const unsigned short* __restrict__ A,
                                                  const unsigned short* __restrict__ Bt,
                                                  const int* __restrict__ sel,
                                                  const float* __restrict__ rw,
                                                  float* __restrict__ out) {
    __shared__ unsigned short lds[3 * 16384];
    const int tid = threadIdx.x;
    const int w = tid >> 6, lane = tid & 63;
    const int wr = w >> 2, wc = w & 3;
    const int lrow = lane & 15, l16 = lane >> 4;
    const int w64 = tid & ~63;

    const int n0 = blockIdx.x * 256, m0 = blockIdx.y * 256;
    const int kbeg = blockIdx.z * (H_ / 4);

    const unsigned short* gA = A + (size_t)m0 * H_ + kbeg;
    const unsigned short* gB = Bt + (size_t)n0 * H_ + kbeg;

    int goff[2], dstA[2], dstB[2];
#pragma unroll
    for (int q = 0; q < 2; q++) {
        int i = q * 512 + tid;
        int row = i >> 2;
        int slot = (i & 3) ^ ((row >> 1) & 3);
        goff[q] = row * H_ + slot * 8;
        dstA[q] = (q * 512 + w64) * 8;
        dstB[q] = 8192 + (q * 512 + w64) * 8;
    }

    int offA[8], offB[4];
#pragma unroll
    for (int i = 0; i < 8; i++) {
        int r = wr * 128 + i * 16 + lrow;
        offA[i] = r * 32 + (l16 ^ ((r >> 1) & 3)) * 8;
    }
#pragma unroll
    for (int j = 0; j < 4; j++) {
        int r = wc * 64 + j * 16 + lrow;
        offB[j] = 8192 + r * 32 + (l16 ^ ((r >> 1) & 3)) * 8;
    }

    float4_t acc[8][4] = {};

#define STAGE2(buf, kt)                                       \
    {                                                         \
        unsigned short* sb_ = lds + (buf) * 16384;            \
        gload_lds16(gA + goff[0] + (kt), sb_ + dstA[0]);      \
        gload_lds16(gA + goff[1] + (kt), sb_ + dstA[1]);      \
        gload_lds16(gB + goff[0] + (kt), sb_ + dstB[0]);      \
        gload_lds16(gB + goff[1] + (kt), sb_ + dstB[1]);      \
    }

    STAGE2(0, 0);
    STAGE2(1, 32);
    asm volatile("s_waitcnt vmcnt(4)" ::: "memory");
    __builtin_amdgcn_s_barrier();

    const int NT = (H_ / 4) / 32;  // 64
    int cur = 0, nx = 2;
    for (int t = 0; t < NT; t++) {
        if (t + 2 < NT) STAGE2(nx, (t + 2) * 32);
        const unsigned short* sb = lds + cur * 16384;
        short8 af[8], bf[4];
#pragma unroll
        for (int i = 0; i < 8; i++) af[i] = *(const short8*)(sb + offA[i]);
#pragma unroll
        for (int j = 0; j < 4; j++) bf[j] = *(const short8*)(sb + offB[j]);
        __builtin_amdgcn_s_setprio(1);
#pragma unroll
        for (int j = 0; j < 4; j++)
#pragma unroll
            for (int i = 0; i < 8; i++)
                acc[i][j] = __builtin_amdgcn_mfma_f32_16x16x32_bf16(af[i], bf[j], acc[i][j], 0, 0, 0);
        __builtin_amdgcn_s_setprio(0);
        if (t + 1 < NT) {
            __builtin_amdgcn_sched_barrier(0);
            if (t + 2 < NT) asm volatile("s_waitcnt vmcnt(4)" ::: "memory");
            else            asm volatile("s_waitcnt vmcnt(0)" ::: "memory");
            __builtin_amdgcn_s_barrier();
        }
        cur = (cur == 2) ? 0 : cur + 1;
        nx  = (nx == 2) ? 0 : nx + 1;
    }
#undef STAGE2

#pragma unroll
    for (int i = 0; i < 8; i++) {
#pragma unroll
        for (int r = 0; r < 4; r++) {
            int m = m0 + wr * 128 + i * 16 + l16 * 4 + r;
            int b = m >> 9, slot = m & 511;
            if (slot < KCAP) {
                int tok = sel[b * SLOTP + slot];
                float wgt = rw[b * SLOTP + slot];
                float* orow = out + ((size_t)(b * S_ + tok)) * D_;
#pragma unroll
                for (int j = 0; j < 4; j++) {
                    int n = n0 + wc * 64 + j * 16 + lrow;
                    atomicAdd(orow + n, wgt * acc[i][j][r]);
                }
            }
        }
    }
}

// ---------------- aux BCE loss ----------------
__global__ __launch_bounds__(256) void k_aux(const float* __restrict__ auxlog,
                                             const int* __restrict__ flags,
                                             float* __restrict__ auxout) {
    int i = blockIdx.x * 256 + threadIdx.x;
    float z = auxlog[i];
    float p = 1.f / (1.f + expf(-z));
    p = fminf(fmaxf(p, 1e-7f), 1.f - 1e-7f);
    int tgt = (i < S_) ? flags[i] : 0;
    float term = tgt ? logf(p) : log1pf(-p);
#pragma unroll
    for (int off = 32; off > 0; off >>= 1) term += __shfl_down(term, off);
    __shared__ float red[4];
    int w = threadIdx.x >> 6, lane = threadIdx.x & 63;
    if (lane == 0) red[w] = term;
    __syncthreads();
    if (threadIdx.x == 0) {
        float s = red[0] + red[1] + red[2] + red[3];
        atomicAdd(auxout, -s * (1.f / 16384.f));
    }
}

extern "C" void kernel_launch(void* const* d_in, const int* in_sizes, int n_in,
                              void* d_out, int out_size, void* d_ws, size_t ws_size,
                              hipStream_t stream) {
    const float* x  = (const float*)d_in[0];
    const float* Wr = (const float*)d_in[1];
    const float* Wa = (const float*)d_in[2];
    const float* W1 = (const float*)d_in[3];
    const float* W2 = (const float*)d_in[4];  // dict order: W2 before W3
    const float* W3 = (const float*)d_in[5];
    float* out = (float*)d_out;

    char* ws = (char*)d_ws;
    unsigned short* WTc  = (unsigned short*)(ws);                // 64MB: interleaved [W1|W3]^T, later W2^T
    unsigned short* Abuf = (unsigned short*)(ws + 67108864ull);  // 8MB:  gathered tokens bf16
    unsigned short* Hbuf = (unsigned short*)(ws + 75497472ull);  // 32MB: SwiGLU hidden bf16
    float* logits = (float*)(ws + 109051904ull);                 // 64KB
    float* auxlog = (float*)(ws + 109117440ull);                 // 64KB
    int*   sel    = (int*)(ws + 109182976ull);                   // 8KB
    float* rwbuf  = (float*)(ws + 109191168ull);                 // 8KB
    int*   flags  = (int*)(ws + 109199360ull);                   // 16KB
    if (ws_size < 109215744ull) return;

    hipMemsetAsync(flags, 0, S_ * sizeof(int), stream);
    hipMemsetAsync(out + (size_t)B_ * S_ * D_, 0, sizeof(float), stream);

    k_transpose_bf16<<<dim3(D_ / 64, H_ / 64), 256, 0, stream>>>(W1, WTc, D_, H_, 0);
    k_transpose_bf16<<<dim3(D_ / 64, H_ / 64), 256, 0, stream>>>(W3, WTc, D_, H_, 16);
    k_router_copy<<<4096, 256, 0, stream>>>(x, Wr, Wa, out, logits, auxlog);
    k_topk<<<4, 1024, 0, stream>>>(logits, sel, rwbuf, flags);
    k_gather<<<MPAD, 256, 0, stream>>>(x, sel, Abuf);
    k_gemm1<<<512, 512, 0, stream>>>(Abuf, WTc, Hbuf);
    k_transpose_bf16<<<dim3(H_ / 64, D_ / 64), 256, 0, stream>>>(W2, WTc, H_, D_, -1);
    k_gemm2<<<dim3(D_ / 256, MPAD / 256, 4), 512, 0, stream>>>(Hbuf, WTc, sel, rwbuf, out);
    k_aux<<<64, 256, 0, stream>>>(auxlog, flags, out + (size_t)B_ * S_ * D_);
}